// Round 1
// 612.626 us; speedup vs baseline: 1.0338x; 1.0338x over previous
//
#include <hip/hip_runtime.h>

// FourierBlock: per (b, c): rfft(4096) -> keep top-16 |X| bins -> irfft.
//
// Round 4 restructure: the inverse FFT of a 16-sparse Hermitian spectrum is
// a 16-term trig sum per output sample. So:
//   1. transpose_LC    : x[B,L,C] -> xT[B,C,L] in d_ws              (unchanged)
//   2. fourier_fwd_topk: forward FFT + top-16 per channel; writes 16
//      (f, alpha, beta) coefficient triplets per (b,c) into the first 256 B
//      of that channel's xT row (the row data is dead after the FFT loads).
//      The entire inverse path (spectrum rebuild, 3 inverse passes, 128 MB
//      store) is deleted.
//   3. synth_kernel    : out[b,l,c] = sum_k alpha_k*cos(2*pi*f_k*l/4096)
//                                   + beta_k*sin(...), computed with exact
//      fp32 angles (f*l < 2^23 -> exact; /4096 pow-2 -> exact; v_fract
//      exact) and hardware v_sin/v_cos. Writes d_out directly in natural
//      [B,L,C] layout -> transpose_CL is eliminated entirely.

#define SWZ(i) ((i) ^ (((i) >> 4) & 15))

__device__ __forceinline__ int drev16(int x) {
  // reverse the three base-16 digits of a 12-bit index (involution)
  return ((x & 15) << 8) | (x & 0xF0) | ((x >> 8) & 15);
}

__device__ __forceinline__ float2 cmulf(float2 a, float c, float s) {
  return make_float2(a.x * c - a.y * s, a.x * s + a.y * c);
}

__device__ __forceinline__ void bfly4(float2& a0, float2& a1, float2& a2, float2& a3) {
  float ar = a0.x + a2.x, ai = a0.y + a2.y;
  float br = a0.x - a2.x, bi = a0.y - a2.y;
  float cr = a1.x + a3.x, ci = a1.y + a3.y;
  float dr = a1.x - a3.x, di = a1.y - a3.y;
  a0 = make_float2(ar + cr, ai + ci);
  a1 = make_float2(br + di, bi - dr);   // b - i*d
  a2 = make_float2(ar - cr, ai - ci);
  a3 = make_float2(br - di, bi + dr);   // b + i*d
}

// 16-point DIF DFT in registers; output slot s holds bin rev4(s).
__device__ __forceinline__ void dft16(float2* v) {
  const float C16[10] = {1.f, 0.9238795325112867f, 0.7071067811865476f, 0.3826834323650898f, 0.f,
                         -0.3826834323650898f, -0.7071067811865476f, -0.9238795325112867f, -1.f,
                         -0.9238795325112867f};
  const float S16[10] = {0.f, -0.3826834323650898f, -0.7071067811865476f, -0.9238795325112867f, -1.f,
                         -0.9238795325112867f, -0.7071067811865476f, -0.3826834323650898f, 0.f,
                         0.3826834323650898f};
  #pragma unroll
  for (int j2 = 0; j2 < 4; j2++) {
    bfly4(v[j2], v[j2 + 4], v[j2 + 8], v[j2 + 12]);
    if (j2 > 0) {
      v[j2 + 4]  = cmulf(v[j2 + 4],  C16[j2],     S16[j2]);
      v[j2 + 8]  = cmulf(v[j2 + 8],  C16[2 * j2], S16[2 * j2]);
      v[j2 + 12] = cmulf(v[j2 + 12], C16[3 * j2], S16[3 * j2]);
    }
  }
  #pragma unroll
  for (int r2 = 0; r2 < 4; r2++) bfly4(v[4 * r2], v[4 * r2 + 1], v[4 * r2 + 2], v[4 * r2 + 3]);
}

// One radix-16 DIF pass over a span; M = twiddle span (0 = last pass, none).
template <int STRIDE, int M>
__device__ __forceinline__ void fft_pass(float2* Zl, int base, int j) {
  const int kRev4[16] = {0, 4, 8, 12, 1, 5, 9, 13, 2, 6, 10, 14, 3, 7, 11, 15};
  float2 v[16];
  #pragma unroll
  for (int p = 0; p < 16; p++) v[p] = Zl[SWZ(base + j + STRIDE * p)];
  dft16(v);
  #pragma unroll
  for (int r = 0; r < 16; r++) {
    float2 u = v[kRev4[r]];
    if (M > 0 && r > 0) {
      int a = (j * r) & (M - 1);
      if (a > M / 2) a -= M;
      float ang = (float)a * (-6.2831853071795864769f / (float)M);
      float s, c;
      __sincosf(ang, &s, &c);
      u = cmulf(u, c, s);
    }
    Zl[SWZ(base + j + STRIDE * r)] = u;
  }
}

// ---------------- transpose kernel ----------------
// x[b][l][c] (C=128 inner) -> xT[b][c][l] (L=4096 inner). Tile: 32 L x 128 C.

__global__ __launch_bounds__(256) void transpose_LC(
    const float4* __restrict__ X4, float4* __restrict__ T4) {
  __shared__ float tile[32 * 132];
  const int t = threadIdx.x;
  const int b = blockIdx.x >> 7;
  const int l0 = (blockIdx.x & 127) << 5;
  const float4* src = X4 + ((size_t)b * 4096 + l0) * 32;
  #pragma unroll
  for (int k = 0; k < 4; k++) {
    int idx = t + 256 * k;
    int l = idx >> 5, cf4 = idx & 31;
    float4 v = src[l * 32 + cf4];
    const float* a = (const float*)&v;
    #pragma unroll
    for (int j = 0; j < 4; j++) tile[l * 132 + 4 * cf4 + j] = a[j];
  }
  __syncthreads();
  float4* dst = T4 + (size_t)b * 128 * 1024 + (l0 >> 2);
  #pragma unroll
  for (int k = 0; k < 4; k++) {
    int idx = t + 256 * k;
    int c = idx >> 3, f = idx & 7;
    float4 w;
    float* o = (float*)&w;
    #pragma unroll
    for (int j = 0; j < 4; j++) o[j] = tile[(4 * f + j) * 132 + c];
    dst[(size_t)c * 1024 + f] = w;
  }
}

// ---------------- forward FFT + top-k kernel (writes coeffs into xT) -------

__global__ __launch_bounds__(512, 2) void fourier_fwd_topk(
    float4* __restrict__ T4) {
  __shared__ float2 Za[4096];
  __shared__ float2 Zb[4096];

  const int tid = threadIdx.x;
  const int b = blockIdx.x >> 5;
  const int q = blockIdx.x & 31;             // 4-channel group
  const size_t rowbase = ((size_t)b * 128 + 4 * q) * 1024;  // float4 units

  // ---- load: 4 contiguous rows; (ch0,ch1) -> Za, (ch2,ch3) -> Zb ----
  #pragma unroll
  for (int k = 0; k < 4; k++) {
    int idx = tid + 512 * k;
    int hf = idx >> 10, p = idx & 1023;
    float4 v0 = T4[rowbase + (size_t)(2 * hf + 0) * 1024 + p];
    float4 v1 = T4[rowbase + (size_t)(2 * hf + 1) * 1024 + p];
    const float* a0 = (const float*)&v0;
    const float* a1 = (const float*)&v1;
    float2* Zt = hf ? Zb : Za;
    #pragma unroll
    for (int j = 0; j < 4; j++) Zt[SWZ(4 * p + j)] = make_float2(a0[j], a1[j]);
  }
  __syncthreads();

  const int h = tid >> 8;      // half: 0 -> Za, 1 -> Zb
  const int lt = tid & 255;    // thread id within half
  float2* Zl = h ? Zb : Za;

  // ---- forward FFT (3 radix-16 passes), output hex-digit-reversed ----
  fft_pass<256, 4096>(Zl, 0, lt);
  __syncthreads();
  fft_pass<16, 256>(Zl, (lt >> 4) << 8, lt & 15);
  __syncthreads();
  fft_pass<1, 0>(Zl, lt << 4, 0);
  __syncthreads();

  // ---- top-16 selection: wave 0 of half = even channel, wave 1 = odd ----
  const int wv = lt >> 6;      // wave within half
  const int lane = lt & 63;

  if (wv < 2) {
    const int ch = wv;
    int rF = 0; float rA = 0.f, rB = 0.f;   // captured winner (lanes 0..15)
    float m2[32];
    #pragma unroll
    for (int k = 0; k < 32; k++) {
      int f = lane + (k << 6);
      float2 P = Zl[SWZ(drev16(f))];
      float2 Q = Zl[SWZ(drev16((4096 - f) & 4095))];
      float xr = ch ? (P.y + Q.y) : (P.x + Q.x);
      float xi = ch ? (Q.x - P.x) : (P.y - Q.y);
      m2[k] = xr * xr + xi * xi;   // 4*|X|^2 (uniform scale, ordering only)
    }
    float m2x = -1.f;              // bin f=2048 (Nyquist), lane 0 only
    if (lane == 0) {
      float2 P = Zl[SWZ(8)];       // drev16(2048) == 8
      float t = ch ? P.y : P.x;
      m2x = 4.f * t * t;
    }
    for (int r = 0; r < 16; r++) {
      float bv = -1e30f; int bf = 0;
      #pragma unroll
      for (int k = 0; k < 32; k++) {
        int f = lane + (k << 6);
        if (m2[k] > bv) { bv = m2[k]; bf = f; }   // ascending k: ties -> lower f
      }
      if (m2x > bv) { bv = m2x; bf = 2048; }
      #pragma unroll
      for (int off = 32; off; off >>= 1) {
        float ov = __shfl_down(bv, off);
        int   of = __shfl_down(bf, off);
        if (ov > bv || (ov == bv && of < bf)) { bv = ov; bf = of; }
      }
      bf = __shfl(bf, 0);          // broadcast winner bin
      if (lane == r) {             // capture X[bf] in lane r's registers
        rF = bf;
        float2 P = Zl[SWZ(drev16(bf))];
        float2 Q = Zl[SWZ(drev16((4096 - bf) & 4095))];
        rA = ch ? 0.5f * (P.y + Q.y) : 0.5f * (P.x + Q.x);
        rB = ch ? 0.5f * (Q.x - P.x) : 0.5f * (P.y - Q.y);
      }
      if (bf == 2048) {
        if (lane == 0) m2x = -2.f;
      } else if ((bf & 63) == lane) {
        int kk = bf >> 6;
        #pragma unroll
        for (int k = 0; k < 32; k++) if (k == kk) m2[k] = -2.f;
      }
    }

    // ---- write 16 coefficient triplets into slots 0..15 of this channel's
    //      xT row (row data is dead: the FFT already consumed it).
    //      out[l] += alpha*cos(2*pi*f*l/4096) + beta*sin(...) with
    //      alpha = w*Re(X), beta = -w*Im(X), w = 1/N (f=0,2048) else 2/N.
    if (lane < 16) {
      const float inv = 2.44140625e-4f;            // 1/4096
      float w = (rF == 0 || rF == 2048) ? inv : 2.f * inv;
      int c = 4 * q + 2 * h + wv;                  // channel index
      T4[((size_t)b * 128 + c) * 1024 + lane] =
          make_float4((float)rF, w * rA, -w * rB, 0.f);
    }
  }
}

// ---------------- sparse synthesis: out[b,l,c] = 16-term trig sum ----------
// Grid: (b, 32-sample L tile). Coeffs for all 128 channels of this b are
// staged in LDS (32 KB source, L2-resident across the 128 tiles per b).
// Each thread owns one channel (c = tid & 127) and 16 L samples; writes are
// scalar but lane-consecutive in c -> perfectly coalesced 512 B rows.

__global__ __launch_bounds__(256) void synth_kernel(
    const float4* __restrict__ T4, float* __restrict__ out) {
  __shared__ float fS[16 * 132];
  __shared__ float aS[16 * 132];
  __shared__ float bS[16 * 132];
  const int t = threadIdx.x;
  const int b = blockIdx.x >> 7;
  const int l0 = (blockIdx.x & 127) << 5;

  // load 128 channels x 16 slots of (f, alpha, beta); 256 B contiguous per row
  #pragma unroll
  for (int i = 0; i < 8; i++) {
    int idx = t + 256 * i;           // 0..2047
    int c = idx >> 4, s = idx & 15;
    float4 v = T4[((size_t)b * 128 + c) * 1024 + s];
    fS[s * 132 + c] = v.x;
    aS[s * 132 + c] = v.y;
    bS[s * 132 + c] = v.z;
  }
  __syncthreads();

  const int c = t & 127;
  const int seg = t >> 7;            // 2 L-samples per pass: l0+2p+seg
  float fk[16], ak[16], bk[16];
  #pragma unroll
  for (int k = 0; k < 16; k++) {     // hoist coeffs to registers (48 VGPR)
    fk[k] = fS[k * 132 + c];
    ak[k] = aS[k * 132 + c];
    bk[k] = bS[k * 132 + c];
  }

  float* op = out + ((size_t)b * 4096 + l0) * 128 + c;
  for (int p = 0; p < 16; p++) {
    float lf = (float)(l0 + 2 * p + seg);
    float acc = 0.f;
    #pragma unroll
    for (int k = 0; k < 16; k++) {
      // angle in revolutions: f*l exact (< 2^23), /4096 exact, fract exact
      float x = fk[k] * lf * 2.44140625e-4f;
      x = x - floorf(x);
      float sn = __builtin_amdgcn_sinf(x);
      float cs = __builtin_amdgcn_cosf(x);
      acc = fmaf(ak[k], cs, fmaf(bk[k], sn, acc));
    }
    op[(size_t)(2 * p + seg) * 128] = acc;
  }
}

extern "C" void kernel_launch(void* const* d_in, const int* in_sizes, int n_in,
                              void* d_out, int out_size, void* d_ws, size_t ws_size,
                              hipStream_t stream) {
  (void)in_sizes; (void)n_in; (void)ws_size; (void)out_size;
  const float4* x = (const float4*)d_in[0];
  float* out = (float*)d_out;
  float4* xT = (float4*)d_ws;   // 64*128*4096 floats = 128 MiB

  transpose_LC<<<dim3(64 * 128), dim3(256), 0, stream>>>(x, xT);
  fourier_fwd_topk<<<dim3(64 * 32), dim3(512), 0, stream>>>(xT);
  synth_kernel<<<dim3(64 * 128), dim3(256), 0, stream>>>(xT, out);
}

// Round 2
// 565.176 us; speedup vs baseline: 1.1206x; 1.0840x over previous
//
#include <hip/hip_runtime.h>

// FourierBlock: per (b, c): rfft(4096) -> keep top-16 |X| bins -> irfft.
//
// Round 5 restructure (2 kernels, no transpose):
//   1. fourier_fwd_topk: reads x[B,L,C] DIRECTLY (one float4 = 4 channels at
//      one time sample), FFT + top-16 per channel, writes 16 (f, alpha, beta)
//      triplets per (b,c) to a compact 2 MB coeff buffer in d_ws.
//      transpose_LC is eliminated; an XCD-contiguous blockIdx remap keeps all
//      32 sibling q-blocks of a batch on one XCD so the 512B-strided loads
//      share cachelines in that XCD's L2.
//   2. synth_kernel: out[b,l,c] = sum_k a_k cos + b_k sin, evaluated with a
//      per-bin phase-rotation recurrence (6 FMA per sample-bin, NO sin/cos in
//      the inner loop). Round-1 profiling showed the per-sample v_sin/v_cos
//      version was trans-pipe issue-bound (~205 us); trans ops drop 8x.

#define SWZ(i) ((i) ^ (((i) >> 4) & 15))

__device__ __forceinline__ int drev16(int x) {
  // reverse the three base-16 digits of a 12-bit index (involution)
  return ((x & 15) << 8) | (x & 0xF0) | ((x >> 8) & 15);
}

__device__ __forceinline__ float2 cmulf(float2 a, float c, float s) {
  return make_float2(a.x * c - a.y * s, a.x * s + a.y * c);
}

__device__ __forceinline__ void bfly4(float2& a0, float2& a1, float2& a2, float2& a3) {
  float ar = a0.x + a2.x, ai = a0.y + a2.y;
  float br = a0.x - a2.x, bi = a0.y - a2.y;
  float cr = a1.x + a3.x, ci = a1.y + a3.y;
  float dr = a1.x - a3.x, di = a1.y - a3.y;
  a0 = make_float2(ar + cr, ai + ci);
  a1 = make_float2(br + di, bi - dr);   // b - i*d
  a2 = make_float2(ar - cr, ai - ci);
  a3 = make_float2(br - di, bi + dr);   // b + i*d
}

// 16-point DIF DFT in registers; output slot s holds bin rev4(s).
__device__ __forceinline__ void dft16(float2* v) {
  const float C16[10] = {1.f, 0.9238795325112867f, 0.7071067811865476f, 0.3826834323650898f, 0.f,
                         -0.3826834323650898f, -0.7071067811865476f, -0.9238795325112867f, -1.f,
                         -0.9238795325112867f};
  const float S16[10] = {0.f, -0.3826834323650898f, -0.7071067811865476f, -0.9238795325112867f, -1.f,
                         -0.9238795325112867f, -0.7071067811865476f, -0.3826834323650898f, 0.f,
                         0.3826834323650898f};
  #pragma unroll
  for (int j2 = 0; j2 < 4; j2++) {
    bfly4(v[j2], v[j2 + 4], v[j2 + 8], v[j2 + 12]);
    if (j2 > 0) {
      v[j2 + 4]  = cmulf(v[j2 + 4],  C16[j2],     S16[j2]);
      v[j2 + 8]  = cmulf(v[j2 + 8],  C16[2 * j2], S16[2 * j2]);
      v[j2 + 12] = cmulf(v[j2 + 12], C16[3 * j2], S16[3 * j2]);
    }
  }
  #pragma unroll
  for (int r2 = 0; r2 < 4; r2++) bfly4(v[4 * r2], v[4 * r2 + 1], v[4 * r2 + 2], v[4 * r2 + 3]);
}

// One radix-16 DIF pass over a span; M = twiddle span (0 = last pass, none).
template <int STRIDE, int M>
__device__ __forceinline__ void fft_pass(float2* Zl, int base, int j) {
  const int kRev4[16] = {0, 4, 8, 12, 1, 5, 9, 13, 2, 6, 10, 14, 3, 7, 11, 15};
  float2 v[16];
  #pragma unroll
  for (int p = 0; p < 16; p++) v[p] = Zl[SWZ(base + j + STRIDE * p)];
  dft16(v);
  #pragma unroll
  for (int r = 0; r < 16; r++) {
    float2 u = v[kRev4[r]];
    if (M > 0 && r > 0) {
      int a = (j * r) & (M - 1);
      if (a > M / 2) a -= M;
      float ang = (float)a * (-6.2831853071795864769f / (float)M);
      float s, c;
      __sincosf(ang, &s, &c);
      u = cmulf(u, c, s);
    }
    Zl[SWZ(base + j + STRIDE * r)] = u;
  }
}

// ---------------- forward FFT + top-k kernel (direct x load) ---------------

__global__ __launch_bounds__(512, 2) void fourier_fwd_topk(
    const float4* __restrict__ X4, float4* __restrict__ W4) {
  __shared__ float2 Za[4096];
  __shared__ float2 Zb[4096];

  const int tid = threadIdx.x;
  // XCD-contiguous remap (bijective: 2048 blocks, 8 XCDs, 256 each):
  // XCD k gets original ids [256k, 256k+256) -> 8 whole batches per XCD,
  // so all 32 q-siblings of a batch share that XCD's L2 lines.
  const int o = ((blockIdx.x & 7) << 8) + (blockIdx.x >> 3);
  const int b = o >> 5;
  const int q = o & 31;             // 4-channel group

  // ---- load: x[b, l, 4q..4q+3] is one float4; (ch0,ch1)->Za, (ch2,ch3)->Zb
  const float4* src = X4 + (size_t)b * 4096 * 32 + q;
  #pragma unroll
  for (int k = 0; k < 8; k++) {
    int l = tid + 512 * k;
    float4 v = src[(size_t)l * 32];
    Za[SWZ(l)] = make_float2(v.x, v.y);
    Zb[SWZ(l)] = make_float2(v.z, v.w);
  }
  __syncthreads();

  const int h = tid >> 8;      // half: 0 -> Za, 1 -> Zb
  const int lt = tid & 255;    // thread id within half
  float2* Zl = h ? Zb : Za;

  // ---- forward FFT (3 radix-16 passes), output hex-digit-reversed ----
  fft_pass<256, 4096>(Zl, 0, lt);
  __syncthreads();
  fft_pass<16, 256>(Zl, (lt >> 4) << 8, lt & 15);
  __syncthreads();
  fft_pass<1, 0>(Zl, lt << 4, 0);
  __syncthreads();

  // ---- top-16 selection: wave 0 of half = even channel, wave 1 = odd ----
  const int wv = lt >> 6;      // wave within half
  const int lane = lt & 63;

  if (wv < 2) {
    const int ch = wv;
    int rF = 0; float rA = 0.f, rB = 0.f;   // captured winner (lanes 0..15)
    float m2[32];
    #pragma unroll
    for (int k = 0; k < 32; k++) {
      int f = lane + (k << 6);
      float2 P = Zl[SWZ(drev16(f))];
      float2 Q = Zl[SWZ(drev16((4096 - f) & 4095))];
      float xr = ch ? (P.y + Q.y) : (P.x + Q.x);
      float xi = ch ? (Q.x - P.x) : (P.y - Q.y);
      m2[k] = xr * xr + xi * xi;   // 4*|X|^2 (uniform scale, ordering only)
    }
    float m2x = -1.f;              // bin f=2048 (Nyquist), lane 0 only
    if (lane == 0) {
      float2 P = Zl[SWZ(8)];       // drev16(2048) == 8
      float t = ch ? P.y : P.x;
      m2x = 4.f * t * t;
    }
    for (int r = 0; r < 16; r++) {
      float bv = -1e30f; int bf = 0;
      #pragma unroll
      for (int k = 0; k < 32; k++) {
        int f = lane + (k << 6);
        if (m2[k] > bv) { bv = m2[k]; bf = f; }   // ascending k: ties -> lower f
      }
      if (m2x > bv) { bv = m2x; bf = 2048; }
      #pragma unroll
      for (int off = 32; off; off >>= 1) {
        float ov = __shfl_down(bv, off);
        int   of = __shfl_down(bf, off);
        if (ov > bv || (ov == bv && of < bf)) { bv = ov; bf = of; }
      }
      bf = __shfl(bf, 0);          // broadcast winner bin
      if (lane == r) {             // capture X[bf] in lane r's registers
        rF = bf;
        float2 P = Zl[SWZ(drev16(bf))];
        float2 Q = Zl[SWZ(drev16((4096 - bf) & 4095))];
        rA = ch ? 0.5f * (P.y + Q.y) : 0.5f * (P.x + Q.x);
        rB = ch ? 0.5f * (Q.x - P.x) : 0.5f * (P.y - Q.y);
      }
      if (bf == 2048) {
        if (lane == 0) m2x = -2.f;
      } else if ((bf & 63) == lane) {
        int kk = bf >> 6;
        #pragma unroll
        for (int k = 0; k < 32; k++) if (k == kk) m2[k] = -2.f;
      }
    }

    // ---- write 16 coefficient triplets for this channel to d_ws.
    //      out[l] += alpha*cos(2*pi*f*l/4096) + beta*sin(...) with
    //      alpha = w*Re(X), beta = -w*Im(X), w = 1/N (f=0,2048) else 2/N.
    if (lane < 16) {
      const float inv = 2.44140625e-4f;            // 1/4096
      float w = (rF == 0 || rF == 2048) ? inv : 2.f * inv;
      int c = 4 * q + 2 * h + wv;                  // channel index
      W4[((size_t)b * 128 + c) * 16 + lane] =
          make_float4((float)rF, w * rA, -w * rB, 0.f);
    }
  }
}

// ---------------- sparse synthesis via phase-rotation recurrence ----------
// Grid: (b, 32-sample L tile). Each thread owns one channel (c = tid & 127)
// and 16 samples at stride 2. Per bin: keep (cos,sin) of the current phase in
// registers and rotate by the fixed per-bin step each sample -> 6 FMA per
// (sample,bin), no trans ops in the loop. fp32 angle args are exact
// (f*l <= 2048*4095 < 2^23; /4096 and /2048 are pow-2 scales; fract exact).
// Drift over 15 rotations ~1e-5 << 2^-8 tolerance.

__global__ __launch_bounds__(256) void synth_kernel(
    const float4* __restrict__ W4, float* __restrict__ out) {
  __shared__ float fS[16 * 132];
  __shared__ float aS[16 * 132];
  __shared__ float bS[16 * 132];
  const int t = threadIdx.x;
  const int b = blockIdx.x >> 7;
  const int l0 = (blockIdx.x & 127) << 5;

  // load 128 channels x 16 slots of (f, alpha, beta); contiguous 256 B/channel
  #pragma unroll
  for (int i = 0; i < 8; i++) {
    int idx = t + 256 * i;           // 0..2047
    int c = idx >> 4, s = idx & 15;
    float4 v = W4[((size_t)b * 128 + c) * 16 + s];
    fS[s * 132 + c] = v.x;
    aS[s * 132 + c] = v.y;
    bS[s * 132 + c] = v.z;
  }
  __syncthreads();

  const int c = t & 127;
  const int seg = t >> 7;            // samples l0 + 2p + seg, p = 0..15
  float ak[16], bk[16], ck[16], sk[16], dc[16], ds[16];
  const float lsf = (float)(l0 + seg);
  #pragma unroll
  for (int k = 0; k < 16; k++) {
    float f = fS[k * 132 + c];
    ak[k] = aS[k * 132 + c];
    bk[k] = bS[k * 132 + c];
    float x0 = f * lsf * 2.44140625e-4f;   // revolutions, exact fp32
    x0 = x0 - floorf(x0);
    ck[k] = __builtin_amdgcn_cosf(x0);
    sk[k] = __builtin_amdgcn_sinf(x0);
    float dx = f * 4.8828125e-4f;          // f*2/4096 revolutions, exact
    dx = dx - floorf(dx);
    dc[k] = __builtin_amdgcn_cosf(dx);
    ds[k] = __builtin_amdgcn_sinf(dx);
  }

  float* op = out + ((size_t)b * 4096 + l0) * 128 + c;
  for (int p = 0; p < 16; p++) {
    float acc = 0.f;
    #pragma unroll
    for (int k = 0; k < 16; k++) {
      acc = fmaf(ak[k], ck[k], fmaf(bk[k], sk[k], acc));
      float nc = fmaf(ck[k], dc[k], -sk[k] * ds[k]);
      float ns = fmaf(sk[k], dc[k],  ck[k] * ds[k]);
      ck[k] = nc; sk[k] = ns;
    }
    op[(size_t)(2 * p + seg) * 128] = acc;
  }
}

extern "C" void kernel_launch(void* const* d_in, const int* in_sizes, int n_in,
                              void* d_out, int out_size, void* d_ws, size_t ws_size,
                              hipStream_t stream) {
  (void)in_sizes; (void)n_in; (void)ws_size; (void)out_size;
  const float4* x = (const float4*)d_in[0];
  float* out = (float*)d_out;
  float4* W = (float4*)d_ws;   // 64*128*16 float4 = 2 MiB coeff buffer

  fourier_fwd_topk<<<dim3(64 * 32), dim3(512), 0, stream>>>(x, W);
  synth_kernel<<<dim3(64 * 128), dim3(256), 0, stream>>>(W, out);
}

// Round 3
// 520.623 us; speedup vs baseline: 1.2165x; 1.0856x over previous
//
#include <hip/hip_runtime.h>

// FourierBlock: per (b, c): rfft(4096) -> keep top-16 |X| bins -> irfft.
//
// Round 6:
//   1. fourier_fwd_topk: reads x[B,L,C] directly (float4 = 4 channels per
//      time sample), FFT + top-16 per channel, writes 16 (f, alpha, beta)
//      triplets per (b,c) to a compact 2 MB coeff buffer. Twiddles now use
//      revolution-form v_sin/v_cos (exact args, no libm range reduction).
//   2. synth_kernel: out[b,l,c] = sum_k a_k cos(w_k l) + b_k sin(w_k l) via
//      Chebyshev three-term recurrence g(l+2) = 2cos(2w) g(l) - g(l-2).
//      Amplitudes fold into the initial values -> per-bin state is only
//      (g_prev, g_cur, T) = 48 VGPRs; inner loop = 1 FMA + 1 add per
//      (sample,bin). Round-2's rotation version carried 96 VGPRs of state
//      and ran ~4x over its VALU roofline (spill-pattern, cf. round-0 note).

#define SWZ(i) ((i) ^ (((i) >> 4) & 15))

__device__ __forceinline__ int drev16(int x) {
  // reverse the three base-16 digits of a 12-bit index (involution)
  return ((x & 15) << 8) | (x & 0xF0) | ((x >> 8) & 15);
}

__device__ __forceinline__ float2 cmulf(float2 a, float c, float s) {
  return make_float2(a.x * c - a.y * s, a.x * s + a.y * c);
}

__device__ __forceinline__ void bfly4(float2& a0, float2& a1, float2& a2, float2& a3) {
  float ar = a0.x + a2.x, ai = a0.y + a2.y;
  float br = a0.x - a2.x, bi = a0.y - a2.y;
  float cr = a1.x + a3.x, ci = a1.y + a3.y;
  float dr = a1.x - a3.x, di = a1.y - a3.y;
  a0 = make_float2(ar + cr, ai + ci);
  a1 = make_float2(br + di, bi - dr);   // b - i*d
  a2 = make_float2(ar - cr, ai - ci);
  a3 = make_float2(br - di, bi + dr);   // b + i*d
}

// 16-point DIF DFT in registers; output slot s holds bin rev4(s).
__device__ __forceinline__ void dft16(float2* v) {
  const float C16[10] = {1.f, 0.9238795325112867f, 0.7071067811865476f, 0.3826834323650898f, 0.f,
                         -0.3826834323650898f, -0.7071067811865476f, -0.9238795325112867f, -1.f,
                         -0.9238795325112867f};
  const float S16[10] = {0.f, -0.3826834323650898f, -0.7071067811865476f, -0.9238795325112867f, -1.f,
                         -0.9238795325112867f, -0.7071067811865476f, -0.3826834323650898f, 0.f,
                         0.3826834323650898f};
  #pragma unroll
  for (int j2 = 0; j2 < 4; j2++) {
    bfly4(v[j2], v[j2 + 4], v[j2 + 8], v[j2 + 12]);
    if (j2 > 0) {
      v[j2 + 4]  = cmulf(v[j2 + 4],  C16[j2],     S16[j2]);
      v[j2 + 8]  = cmulf(v[j2 + 8],  C16[2 * j2], S16[2 * j2]);
      v[j2 + 12] = cmulf(v[j2 + 12], C16[3 * j2], S16[3 * j2]);
    }
  }
  #pragma unroll
  for (int r2 = 0; r2 < 4; r2++) bfly4(v[4 * r2], v[4 * r2 + 1], v[4 * r2 + 2], v[4 * r2 + 3]);
}

// One radix-16 DIF pass over a span; M = twiddle span (0 = last pass, none).
// Twiddle angle is a/M revolutions, a in [0, M): exact fp32, already in
// [0,1) -> feed v_sin/v_cos (period-1 hardware trig) directly.
template <int STRIDE, int M>
__device__ __forceinline__ void fft_pass(float2* Zl, int base, int j) {
  const int kRev4[16] = {0, 4, 8, 12, 1, 5, 9, 13, 2, 6, 10, 14, 3, 7, 11, 15};
  float2 v[16];
  #pragma unroll
  for (int p = 0; p < 16; p++) v[p] = Zl[SWZ(base + j + STRIDE * p)];
  dft16(v);
  #pragma unroll
  for (int r = 0; r < 16; r++) {
    float2 u = v[kRev4[r]];
    if (M > 0 && r > 0) {
      int a = (j * r) & (M - 1);
      float x = (float)a * (1.0f / (float)M);       // revolutions, exact
      float s = -__builtin_amdgcn_sinf(x);          // e^{-2pi i x}
      float c =  __builtin_amdgcn_cosf(x);
      u = cmulf(u, c, s);
    }
    Zl[SWZ(base + j + STRIDE * r)] = u;
  }
}

// ---------------- forward FFT + top-k kernel (direct x load) ---------------

__global__ __launch_bounds__(512, 2) void fourier_fwd_topk(
    const float4* __restrict__ X4, float4* __restrict__ W4) {
  __shared__ float2 Za[4096];
  __shared__ float2 Zb[4096];

  const int tid = threadIdx.x;
  // XCD-contiguous remap (bijective: 2048 blocks, 8 XCDs, 256 each):
  // XCD k gets original ids [256k, 256k+256) -> 8 whole batches per XCD,
  // so all 32 q-siblings of a batch share that XCD's L2 lines.
  const int o = ((blockIdx.x & 7) << 8) + (blockIdx.x >> 3);
  const int b = o >> 5;
  const int q = o & 31;             // 4-channel group

  // ---- load: x[b, l, 4q..4q+3] is one float4; (ch0,ch1)->Za, (ch2,ch3)->Zb
  const float4* src = X4 + (size_t)b * 4096 * 32 + q;
  #pragma unroll
  for (int k = 0; k < 8; k++) {
    int l = tid + 512 * k;
    float4 v = src[(size_t)l * 32];
    Za[SWZ(l)] = make_float2(v.x, v.y);
    Zb[SWZ(l)] = make_float2(v.z, v.w);
  }
  __syncthreads();

  const int h = tid >> 8;      // half: 0 -> Za, 1 -> Zb
  const int lt = tid & 255;    // thread id within half
  float2* Zl = h ? Zb : Za;

  // ---- forward FFT (3 radix-16 passes), output hex-digit-reversed ----
  fft_pass<256, 4096>(Zl, 0, lt);
  __syncthreads();
  fft_pass<16, 256>(Zl, (lt >> 4) << 8, lt & 15);
  __syncthreads();
  fft_pass<1, 0>(Zl, lt << 4, 0);
  __syncthreads();

  // ---- top-16 selection: wave 0 of half = even channel, wave 1 = odd ----
  const int wv = lt >> 6;      // wave within half
  const int lane = lt & 63;

  if (wv < 2) {
    const int ch = wv;
    int rF = 0; float rA = 0.f, rB = 0.f;   // captured winner (lanes 0..15)
    float m2[32];
    #pragma unroll
    for (int k = 0; k < 32; k++) {
      int f = lane + (k << 6);
      float2 P = Zl[SWZ(drev16(f))];
      float2 Q = Zl[SWZ(drev16((4096 - f) & 4095))];
      float xr = ch ? (P.y + Q.y) : (P.x + Q.x);
      float xi = ch ? (Q.x - P.x) : (P.y - Q.y);
      m2[k] = xr * xr + xi * xi;   // 4*|X|^2 (uniform scale, ordering only)
    }
    float m2x = -1.f;              // bin f=2048 (Nyquist), lane 0 only
    if (lane == 0) {
      float2 P = Zl[SWZ(8)];       // drev16(2048) == 8
      float t = ch ? P.y : P.x;
      m2x = 4.f * t * t;
    }
    for (int r = 0; r < 16; r++) {
      float bv = -1e30f; int bf = 0;
      #pragma unroll
      for (int k = 0; k < 32; k++) {
        int f = lane + (k << 6);
        if (m2[k] > bv) { bv = m2[k]; bf = f; }   // ascending k: ties -> lower f
      }
      if (m2x > bv) { bv = m2x; bf = 2048; }
      #pragma unroll
      for (int off = 32; off; off >>= 1) {
        float ov = __shfl_down(bv, off);
        int   of = __shfl_down(bf, off);
        if (ov > bv || (ov == bv && of < bf)) { bv = ov; bf = of; }
      }
      bf = __shfl(bf, 0);          // broadcast winner bin
      if (lane == r) {             // capture X[bf] in lane r's registers
        rF = bf;
        float2 P = Zl[SWZ(drev16(bf))];
        float2 Q = Zl[SWZ(drev16((4096 - bf) & 4095))];
        rA = ch ? 0.5f * (P.y + Q.y) : 0.5f * (P.x + Q.x);
        rB = ch ? 0.5f * (Q.x - P.x) : 0.5f * (P.y - Q.y);
      }
      if (bf == 2048) {
        if (lane == 0) m2x = -2.f;
      } else if ((bf & 63) == lane) {
        int kk = bf >> 6;
        #pragma unroll
        for (int k = 0; k < 32; k++) if (k == kk) m2[k] = -2.f;
      }
    }

    // ---- write 16 coefficient triplets for this channel to d_ws.
    //      out[l] += alpha*cos(2*pi*f*l/4096) + beta*sin(...) with
    //      alpha = w*Re(X), beta = -w*Im(X), w = 1/N (f=0,2048) else 2/N.
    if (lane < 16) {
      const float inv = 2.44140625e-4f;            // 1/4096
      float w = (rF == 0 || rF == 2048) ? inv : 2.f * inv;
      int c = 4 * q + 2 * h + wv;                  // channel index
      W4[((size_t)b * 128 + c) * 16 + lane] =
          make_float4((float)rF, w * rA, -w * rB, 0.f);
    }
  }
}

// ---------------- sparse synthesis via Chebyshev recurrence ----------------
// Grid: (b, 32-sample L tile). Thread owns channel c = tid & 127 and 16
// samples at stride 2 (l = l0 + 2p + seg). Per bin k the sinusoid
// g(l) = a cos(w l) + b sin(w l) obeys g(l+2) = T g(l) - g(l-2), T=2cos(2w).
// Amplitudes fold into the initial values: state = (g_prev, g_cur, T) ->
// 48 VGPRs, inner loop = 1 fma + 1 add per (sample,bin). Angle args exact
// in fp32 (f*l <= 2048*4095 < 2^23; /4096, /2048 pow-2; fract exact).
// Recurrence drift over 16 steps ~1e-5 << 2^-8 tolerance.

__global__ __launch_bounds__(256) void synth_kernel(
    const float4* __restrict__ W4, float* __restrict__ out) {
  __shared__ float fS[16 * 132];
  __shared__ float aS[16 * 132];
  __shared__ float bS[16 * 132];
  const int t = threadIdx.x;
  const int b = blockIdx.x >> 7;
  const int l0 = (blockIdx.x & 127) << 5;

  // load 128 channels x 16 slots of (f, alpha, beta); contiguous 256 B/channel
  #pragma unroll
  for (int i = 0; i < 8; i++) {
    int idx = t + 256 * i;           // 0..2047
    int c = idx >> 4, s = idx & 15;
    float4 v = W4[((size_t)b * 128 + c) * 16 + s];
    fS[s * 132 + c] = v.x;
    aS[s * 132 + c] = v.y;
    bS[s * 132 + c] = v.z;
  }
  __syncthreads();

  const int c = t & 127;
  const int seg = t >> 7;            // samples l0 + 2p + seg, p = 0..15
  float u[16], v[16], T[16];         // g_cur, g_prev, 2cos(2w)
  const float lsf = (float)(l0 + seg);
  #pragma unroll
  for (int k = 0; k < 16; k++) {
    float f  = fS[k * 132 + c];
    float a  = aS[k * 132 + c];
    float bb = bS[k * 132 + c];
    float x0 = f * lsf * 2.44140625e-4f;   // f*(l0+seg)/4096 rev, exact
    x0 -= floorf(x0);
    float c0 = __builtin_amdgcn_cosf(x0);
    float s0 = __builtin_amdgcn_sinf(x0);
    float dx = f * 4.8828125e-4f;          // 2f/4096 rev, exact
    dx -= floorf(dx);
    float c2 = __builtin_amdgcn_cosf(dx);
    float s2 = __builtin_amdgcn_sinf(dx);
    float G = fmaf(a, c0, bb * s0);        // g(l_init)
    float H = fmaf(bb, c0, -a * s0);       // b cos - a sin
    u[k] = G;                              // g_cur  = g(l_init)
    v[k] = fmaf(G, c2, -H * s2);           // g_prev = g(l_init - 2)
    T[k] = 2.f * c2;
  }

  float* op = out + ((size_t)b * 4096 + l0) * 128 + c;
  #pragma unroll
  for (int p = 0; p < 16; p += 2) {        // parity-unrolled: static indexing
    float acc0 = 0.f, acc1 = 0.f;
    #pragma unroll
    for (int k = 0; k < 16; k++) {
      acc0 += u[k];
      v[k] = fmaf(T[k], u[k], -v[k]);      // v <- g(p+1)
    }
    #pragma unroll
    for (int k = 0; k < 16; k++) {
      acc1 += v[k];
      u[k] = fmaf(T[k], v[k], -u[k]);      // u <- g(p+2)
    }
    op[(size_t)(2 * p + seg) * 128] = acc0;
    op[(size_t)(2 * (p + 1) + seg) * 128] = acc1;
  }
}

extern "C" void kernel_launch(void* const* d_in, const int* in_sizes, int n_in,
                              void* d_out, int out_size, void* d_ws, size_t ws_size,
                              hipStream_t stream) {
  (void)in_sizes; (void)n_in; (void)ws_size; (void)out_size;
  const float4* x = (const float4*)d_in[0];
  float* out = (float*)d_out;
  float4* W = (float4*)d_ws;   // 64*128*16 float4 = 2 MiB coeff buffer

  fourier_fwd_topk<<<dim3(64 * 32), dim3(512), 0, stream>>>(x, W);
  synth_kernel<<<dim3(64 * 128), dim3(256), 0, stream>>>(W, out);
}